// Round 12
// baseline (104.345 us; speedup 1.0000x reference)
//
#include <hip/hip_runtime.h>
#include <math.h>

#define TSEQ 2048
#define NB   2
#define DM   1024
#define NH   16
#define DH   64
#define GN_EPS 1e-5f

typedef short v8s __attribute__((ext_vector_type(8)));
typedef short v4s __attribute__((ext_vector_type(4)));
typedef float v4f __attribute__((ext_vector_type(4)));

__device__ __forceinline__ short f2bf(float f) {
    union { float f; unsigned u; } c; c.f = f;
    unsigned u = c.u;
    unsigned r = (u + 0x7fffu + ((u >> 16) & 1u)) >> 16;   // RNE
    return (short)r;
}
__device__ __forceinline__ float bf2f(short s) {
    union { unsigned u; float f; } c; c.u = ((unsigned)(unsigned short)s) << 16;
    return c.f;
}

// pack two f32 -> two bf16 in one instruction (no builtin on gfx950)
__device__ __forceinline__ unsigned cvtpk_bf16(float lo, float hi) {
    unsigned r;
    asm("v_cvt_pk_bf16_f32 %0, %1, %2" : "=v"(r) : "v"(lo), "v"(hi));
    return r;
}

// async global->LDS, 16B per lane.  LDS dest = wave-uniform base + lane*16.
__device__ __forceinline__ void gl_lds16(const void* g, void* p) {
    __builtin_amdgcn_global_load_lds(
        (const __attribute__((address_space(1))) void*)g,
        (__attribute__((address_space(3))) void*)p, 16, 0, 0);
}

// ---------------------------------------------------------------------------
// cast x and the 4 weight matrices to bf16
// ---------------------------------------------------------------------------
__global__ __launch_bounds__(256) void cast_kernel(
    const float* __restrict__ x,
    const float* __restrict__ Wq, const float* __restrict__ Wk,
    const float* __restrict__ Wv, const float* __restrict__ Wo,
    short* __restrict__ xbf, short* __restrict__ wbf)
{
    const int NX = NB * TSEQ * DM;            // 4,194,304
    const int NW = DM * DM;                   // 1,048,576
    const int total4 = (NX + 4 * NW) / 4;     // 2,097,152
    for (int i = blockIdx.x * 256 + threadIdx.x; i < total4;
         i += gridDim.x * 256) {
        int e = i * 4;
        const float* src; short* dst;
        if (e < NX) { src = x + e; dst = xbf + e; }
        else {
            int o = e - NX;
            int w = o >> 20;
            int r = o & (NW - 1);
            src = (w == 0 ? Wq : w == 1 ? Wk : w == 2 ? Wv : Wo) + r;
            dst = wbf + o;
        }
        v4f v = *(const v4f*)src;
        v4s s;
        #pragma unroll
        for (int j = 0; j < 4; ++j) s[j] = f2bf(v[j]);
        *(v4s*)dst = s;
    }
}

// ---------------------------------------------------------------------------
// QKV projection as ONE 4096x3072x1024 GEMM, 256x256 tile, BK=64, 8 waves,
// 8-phase-style schedule: per K-tile 4 quadrant phases, each issuing one
// stage-group of tile t+1 (2 x global_load_lds), counted vmcnt(4) (never 0
// in steady state), raw s_barrier (3 per tile), setprio around MFMA.
// LDS 128KB double buffer, linear dest + pre-XOR-swizzled source, swizzled
// ds_read_b128 (conflict-free).  grid 192 (XCD-chunked), 512 threads.
// Epilogue per n-range: z=0 -> Q' = Q*gamma^(t&63)/8 (Qb row-major)
//                       z=1 -> K' = K*gamma^-(t&63) (Kb row-major + Kt transposed)
//                       z=2 -> V -> Vt[b][dm][t] transposed
// ---------------------------------------------------------------------------
__global__ __launch_bounds__(512, 2) void gemm_qkv_8ph(
    const short* __restrict__ xbf, const short* __restrict__ wbf,
    short* __restrict__ Qb, short* __restrict__ Kb,
    short* __restrict__ Kt, short* __restrict__ Vt)
{
    __shared__ char ldsb[131072];              // [2][A 32KB | B 32KB]

    const int bid = blockIdx.x;                // 0..191
    const int gidx = (bid & 7) * 24 + (bid >> 3);
    const int mt = gidx / 12, nt = gidx % 12;
    const int m0 = mt * 256, n0 = nt * 256;    // n0 in [0,3072)

    const int tid = threadIdx.x, l = tid & 63, w = tid >> 6;
    const int lr = l & 15, kgrp = l >> 4;
    const int wm = w >> 2, wn = w & 3;
    const int swzl = (lr & 7) << 4;

    const char* Axg = (const char*)xbf;        // A rows: m0 + row
    const char* Bwg = (const char*)wbf;        // B rows: n0 + row (Wq|Wk|Wv)

    // ---- stage descriptors: group chunks c = w*64 + l + 512q ----
    size_t srcA1[2], srcB2[2];
    int    dstA1[2], dstB2[2];
    #pragma unroll
    for (int q = 0; q < 2; ++q) {
        int c = w * 64 + l + 512 * q;
        int u = c & 7;
        int rowA = ((c >> 9) << 7) + ((c >> 3) & 63);        // G1 rows
        srcA1[q] = (size_t)(m0 + rowA) * 2048 + (size_t)((u ^ (rowA & 7)) << 4);
        int rowB = ((c >> 8) << 6) + ((c >> 3) & 31);        // G2 rows
        srcB2[q] = (size_t)(n0 + rowB) * 2048 + (size_t)((u ^ (rowB & 7)) << 4);
        // wave-uniform dest bases (lane*16 added by HW)
        int rA0 = q * 128 + w * 8;
        dstA1[q] = rA0 * 128;
        int rB0 = 64 * ((w >> 2) + 2 * q) + (w & 3) * 8;
        dstB2[q] = 32768 + rB0 * 128;
    }

#define ISSUE_G1(tt) { int bo = ((tt) & 1) * 65536; size_t kb = (size_t)(tt) * 128; \
    gl_lds16(Axg + srcA1[0] + kb, ldsb + bo + dstA1[0]); \
    gl_lds16(Axg + srcA1[1] + kb, ldsb + bo + dstA1[1]); }
#define ISSUE_G2(tt) { int bo = ((tt) & 1) * 65536; size_t kb = (size_t)(tt) * 128; \
    gl_lds16(Bwg + srcB2[0] + kb, ldsb + bo + dstB2[0]); \
    gl_lds16(Bwg + srcB2[1] + kb, ldsb + bo + dstB2[1]); }
#define ISSUE_G3(tt) { int bo = ((tt) & 1) * 65536; size_t kb = (size_t)(tt) * 128; \
    gl_lds16(Bwg + srcB2[0] + 32 * 2048 + kb, ldsb + bo + dstB2[0] + 32 * 128); \
    gl_lds16(Bwg + srcB2[1] + 32 * 2048 + kb, ldsb + bo + dstB2[1] + 32 * 128); }
#define ISSUE_G4(tt) { int bo = ((tt) & 1) * 65536; size_t kb = (size_t)(tt) * 128; \
    gl_lds16(Axg + srcA1[0] + 64 * 2048 + kb, ldsb + bo + dstA1[0] + 64 * 128); \
    gl_lds16(Axg + srcA1[1] + 64 * 2048 + kb, ldsb + bo + dstA1[1] + 64 * 128); }

    v4f acc[8][4];
    #pragma unroll
    for (int i = 0; i < 8; ++i)
        #pragma unroll
        for (int j = 0; j < 4; ++j) acc[i][j] = (v4f){0.f, 0.f, 0.f, 0.f};

    // prologue: stage all 4 groups of tile 0
    ISSUE_G1(0); ISSUE_G2(0); ISSUE_G3(0); ISSUE_G4(0);

    v8s af[4][2], bfr[4][2];

#define LDA(frl, frbase) { \
    const char* rp = Ab + (wm * 128 + ((frbase) + (frl)) * 16 + lr) * 128; \
    af[frl][0] = *(const v8s*)(rp + ((kgrp * 16) ^ swzl)); \
    af[frl][1] = *(const v8s*)(rp + ((64 + kgrp * 16) ^ swzl)); }
#define LDB(fc) { \
    const char* rp = Bb + (wn * 64 + (fc) * 16 + lr) * 128; \
    bfr[fc][0] = *(const v8s*)(rp + ((kgrp * 16) ^ swzl)); \
    bfr[fc][1] = *(const v8s*)(rp + ((64 + kgrp * 16) ^ swzl)); }
#define MM(frl, frbase, fc) \
    acc[(frbase) + (frl)][fc] = __builtin_amdgcn_mfma_f32_16x16x32_bf16( \
        af[frl][0], bfr[fc][0], acc[(frbase) + (frl)][fc], 0, 0, 0); \
    acc[(frbase) + (frl)][fc] = __builtin_amdgcn_mfma_f32_16x16x32_bf16( \
        af[frl][1], bfr[fc][1], acc[(frbase) + (frl)][fc], 0, 0, 0);

    #pragma unroll 2
    for (int t = 0; t < 16; ++t) {
        const char* Ab = ldsb + (t & 1) * 65536;
        const char* Bb = Ab + 32768;

        // ---- phase 1: quadrant A03 x B01 ----
        asm volatile("s_waitcnt vmcnt(4)" ::: "memory");
        __builtin_amdgcn_s_barrier();
        __builtin_amdgcn_sched_barrier(0);
        if (t < 15) ISSUE_G1(t + 1);
        #pragma unroll
        for (int frl = 0; frl < 4; ++frl) LDA(frl, 0);
        LDB(0); LDB(1);
        __builtin_amdgcn_s_setprio(1);
        #pragma unroll
        for (int frl = 0; frl < 4; ++frl) { MM(frl, 0, 0); MM(frl, 0, 1); }
        __builtin_amdgcn_s_setprio(0);

        // ---- phase 2: quadrant A03 x B23 ----
        if (t < 15) { asm volatile("s_waitcnt vmcnt(4)" ::: "memory"); }
        else        { asm volatile("s_waitcnt vmcnt(2)" ::: "memory"); }
        __builtin_amdgcn_s_barrier();
        __builtin_amdgcn_sched_barrier(0);
        if (t < 15) ISSUE_G2(t + 1);
        LDB(2); LDB(3);
        __builtin_amdgcn_s_setprio(1);
        #pragma unroll
        for (int frl = 0; frl < 4; ++frl) { MM(frl, 0, 2); MM(frl, 0, 3); }
        __builtin_amdgcn_s_setprio(0);

        // ---- phase 3: quadrant A47 x B01 ----
        if (t < 15) { asm volatile("s_waitcnt vmcnt(4)" ::: "memory"); }
        else        { asm volatile("s_waitcnt vmcnt(0)" ::: "memory"); }
        __builtin_amdgcn_s_barrier();
        __builtin_amdgcn_sched_barrier(0);
        if (t < 15) ISSUE_G3(t + 1);
        #pragma unroll
        for (int frl = 0; frl < 4; ++frl) LDA(frl, 4);
        __builtin_amdgcn_s_setprio(1);
        #pragma unroll
        for (int frl = 0; frl < 4; ++frl) { MM(frl, 4, 0); MM(frl, 4, 1); }
        __builtin_amdgcn_s_setprio(0);

        // ---- phase 4: quadrant A47 x B23 (no barrier, no new data needs) ----
        if (t < 15) ISSUE_G4(t + 1);
        __builtin_amdgcn_s_setprio(1);
        #pragma unroll
        for (int frl = 0; frl < 4; ++frl) { MM(frl, 4, 2); MM(frl, 4, 3); }
        __builtin_amdgcn_s_setprio(0);
    }

    // ---------------- epilogue ----------------
    const int zz = n0 >> 10;                   // 0=Q 1=K 2=V
    const int ncol0 = n0 & 1023;
    const int rg = kgrp * 4;
    const int rowbase = m0 + wm * 128;

    if (zz == 0) {
        #pragma unroll
        for (int fc = 0; fc < 4; ++fc) {
            int coll = ncol0 + wn * 64 + fc * 16 + lr;
            int hh = coll >> 6;
            float l2 = log2f(1.0f - exp2f(-5.0f - (float)hh));
            float s1 = exp2f(l2);
            float s16 = exp2f(l2 * 16.0f);
            float e0 = exp2f(fmaf(l2, (float)rg, -3.0f));   // 1/8 folded
            float p16[4] = {1.f, s16, s16 * s16, s16 * s16 * s16};
            float pr[4]  = {1.f, s1, s1 * s1, s1 * s1 * s1};
            #pragma unroll
            for (int fr = 0; fr < 8; ++fr) {
                float fb = e0 * p16[fr & 3];
                int row = rowbase + fr * 16 + rg;
                #pragma unroll
                for (int r = 0; r < 4; ++r)
                    Qb[(size_t)(row + r) * DM + coll] =
                        f2bf(acc[fr][fc][r] * (fb * pr[r]));
            }
        }
    } else if (zz == 1) {
        #pragma unroll
        for (int fc = 0; fc < 4; ++fc) {
            int coll = ncol0 + wn * 64 + fc * 16 + lr;
            int hh = coll >> 6;
            float l2 = -log2f(1.0f - exp2f(-5.0f - (float)hh));
            float s1 = exp2f(l2);
            float s16 = exp2f(l2 * 16.0f);
            float e0 = exp2f(l2 * (float)rg);
            float p16[4] = {1.f, s16, s16 * s16, s16 * s16 * s16};
            float pr[4]  = {1.f, s1, s1 * s1, s1 * s1 * s1};
            #pragma unroll
            for (int fr = 0; fr < 8; ++fr) {
                float fb = e0 * p16[fr & 3];
                int row = rowbase + fr * 16 + rg;
                int bidx = row >> 11, tb = row & (TSEQ - 1);
                v4s pk;
                #pragma unroll
                for (int r = 0; r < 4; ++r) {
                    short bv = f2bf(acc[fr][fc][r] * (fb * pr[r]));
                    Kb[(size_t)(row + r) * DM + coll] = bv;
                    pk[r] = bv;
                }
                *(v4s*)(Kt + ((size_t)bidx << 21) + ((size_t)coll << 11) + tb) = pk;
            }
        }
    } else {
        #pragma unroll
        for (int fc = 0; fc < 4; ++fc) {
            int coll = ncol0 + wn * 64 + fc * 16 + lr;
            #pragma unroll
            for (int fr = 0; fr < 8; ++fr) {
                int row = rowbase + fr * 16 + rg;
                int bidx = row >> 11, tb = row & (TSEQ - 1);
                v4s pk;
                #pragma unroll
                for (int r = 0; r < 4; ++r) pk[r] = f2bf(acc[fr][fc][r]);
                *(v4s*)(Vt + ((size_t)bidx << 21) + ((size_t)coll << 11) + tb) = pk;
            }
        }
    }
#undef ISSUE_G1
#undef ISSUE_G2
#undef ISSUE_G3
#undef ISSUE_G4
#undef LDA
#undef LDB
#undef MM
}

// ---------------------------------------------------------------------------
// chunk_kv: per (b,h,chunk) compute A_c^T[dv][dk] = sum_jl V[jl][dv]*K'[jl][dk]
// ---------------------------------------------------------------------------
__global__ __launch_bounds__(256, 2) void chunk_kv(
    const short* __restrict__ Kt, const short* __restrict__ Vt,
    short* __restrict__ At)
{
    const int bid = blockIdx.x;                // 1024
    const int c = bid & 31, bh = bid >> 5;
    const int b = bh >> 4, h = bh & 15;
    const int tid = threadIdx.x, l = tid & 63, w = tid >> 6;
    const int lr = l & 15, g = l >> 4;

    const size_t rowbase = ((size_t)b * DM + h * 64);

    v8s kf[2], vf[4][2];
    {
        const short* kp = Kt + (rowbase + 16 * w + lr) * TSEQ + 64 * c;
        kf[0] = *(const v8s*)(kp + g * 8);
        kf[1] = *(const v8s*)(kp + 32 + g * 8);
    }
    #pragma unroll
    for (int j = 0; j < 4; ++j) {
        const short* vp = Vt + (rowbase + j * 16 + lr) * TSEQ + 64 * c;
        vf[j][0] = *(const v8s*)(vp + g * 8);
        vf[j][1] = *(const v8s*)(vp + 32 + g * 8);
    }

    v4f acc[4];
    #pragma unroll
    for (int j = 0; j < 4; ++j) acc[j] = (v4f){0.f, 0.f, 0.f, 0.f};

    #pragma unroll
    for (int j = 0; j < 4; ++j) {
        acc[j] = __builtin_amdgcn_mfma_f32_16x16x32_bf16(kf[0], vf[j][0], acc[j], 0, 0, 0);
        acc[j] = __builtin_amdgcn_mfma_f32_16x16x32_bf16(kf[1], vf[j][1], acc[j], 0, 0, 0);
    }

    short* Ab = At + (((size_t)bh * 32 + c) << 12);
    #pragma unroll
    for (int j = 0; j < 4; ++j) {
        v4s pk;
        #pragma unroll
        for (int r = 0; r < 4; ++r) pk[r] = f2bf(acc[j][r]);
        *(v4s*)(Ab + (j * 16 + lr) * 64 + 16 * w + g * 4) = pk;
    }
}

// ---------------------------------------------------------------------------
// chunk_scan: State_c = gamma^64 * (State_{c-1} + A_{c-1})
// ---------------------------------------------------------------------------
__global__ __launch_bounds__(256) void chunk_scan(
    const short* __restrict__ At, short* __restrict__ St)
{
    const int idx = blockIdx.x * 256 + threadIdx.x;   // 131072
    const int bh = idx >> 12;
    const int h  = bh & 15;
    const float l2g = log2f(1.0f - exp2f(-5.0f - (float)h));
    const float g64 = exp2f(l2g * 64.0f);

    const size_t base = ((size_t)bh << 17) + (idx & 4095);
    float state = 0.0f;
    #pragma unroll
    for (int c = 1; c < 32; ++c) {
        float a = bf2f(At[base + ((size_t)(c - 1) << 12)]);
        state = g64 * (state + a);
        St[base + ((size_t)c << 12)] = f2bf(state);
    }
}

// ---------------------------------------------------------------------------
// chunk_out: Y_c^T = StateT_c.Q'^T + V^T.(mask(Q'K'^T));  GN partials ->
// plain stores to psums (no atomics).
// ---------------------------------------------------------------------------
__global__ __launch_bounds__(256, 2) void chunk_out(
    const short* __restrict__ Qb, const short* __restrict__ Kb,
    const short* __restrict__ Vt, const short* __restrict__ St,
    float* __restrict__ Y, float* __restrict__ psums)
{
    const int bid = blockIdx.x;                 // 1024
    const int xcd = bid & 7, r8 = bid >> 3;
    const int bh  = xcd * 4 + (r8 >> 5);
    const int c   = r8 & 31;
    const int b = bh >> 4, h = bh & 15;
    const int tid = threadIdx.x, l = tid & 63, w = tid >> 6;
    const int lr = l & 15, g = l >> 4;

    __shared__ short strip[64 * 64];
    __shared__ float tr[64][68];
    __shared__ float red[8];

    const size_t rowQK = ((size_t)(b * TSEQ + 64 * c)) * DM + h * 64;

    v8s qf[4][2];
    #pragma unroll
    for (int j = 0; j < 4; ++j) {
        const short* qp = Qb + rowQK + (size_t)(j * 16 + lr) * DM;
        qf[j][0] = *(const v8s*)(qp + g * 8);
        qf[j][1] = *(const v8s*)(qp + 32 + g * 8);
    }
    v8s kf0, kf1;
    {
        const short* kp = Kb + rowQK + (size_t)(16 * w + lr) * DM;
        kf0 = *(const v8s*)(kp + g * 8);
        kf1 = *(const v8s*)(kp + 32 + g * 8);
    }
    v8s sf0 = {}, sf1 = {};
    if (c > 0) {
        const short* sp = St + (((size_t)bh * 32 + c) << 12) + (16 * w + lr) * 64;
        sf0 = *(const v8s*)(sp + g * 8);
        sf1 = *(const v8s*)(sp + 32 + g * 8);
    }
    v8s vf0, vf1;
    {
        const short* vp = Vt + ((size_t)(b * DM + h * 64) + 16 * w + lr) * TSEQ
                          + 64 * c;
        vf0 = *(const v8s*)(vp + g * 8);
        vf1 = *(const v8s*)(vp + 32 + g * 8);
    }

    v4f s[4];
    #pragma unroll
    for (int j = 0; j < 4; ++j) {
        v4f a = (v4f){0.f, 0.f, 0.f, 0.f};
        a = __builtin_amdgcn_mfma_f32_16x16x32_bf16(kf0, qf[j][0], a, 0, 0, 0);
        a = __builtin_amdgcn_mfma_f32_16x16x32_bf16(kf1, qf[j][1], a, 0, 0, 0);
        s[j] = a;
    }

    v4f y[4];
    #pragma unroll
    for (int j = 0; j < 4; ++j) y[j] = (v4f){0.f, 0.f, 0.f, 0.f};
    if (c > 0) {
        #pragma unroll
        for (int j = 0; j < 4; ++j) {
            y[j] = __builtin_amdgcn_mfma_f32_16x16x32_bf16(sf0, qf[j][0], y[j], 0, 0, 0);
            y[j] = __builtin_amdgcn_mfma_f32_16x16x32_bf16(sf1, qf[j][1], y[j], 0, 0, 0);
        }
    }

    #pragma unroll
    for (int j = 0; j < 4; ++j) {
        v4f vv = s[j];
        #pragma unroll
        for (int r = 0; r < 4; ++r)
            if ((j * 16 + lr) - (16 * w + g * 4 + r) < 0) vv[r] = 0.0f;
        unsigned u0 = cvtpk_bf16(vv[0], vv[1]);
        unsigned u1 = cvtpk_bf16(vv[2], vv[3]);
        int byte = ((j * 16 + lr) * 128 + 32 * w + g * 8) ^ ((lr & 7) << 4);
        *(unsigned long long*)((char*)strip + byte) =
            (unsigned long long)u0 | ((unsigned long long)u1 << 32);
    }
    __syncthreads();

    #pragma unroll
    for (int j = 0; j < 4; ++j) {
        int rb = (j * 16 + lr) * 128;
        int sw = (lr & 7) << 4;
        v8s sB0 = *(const v8s*)((char*)strip + ((rb + g * 16) ^ sw));
        v8s sB1 = *(const v8s*)((char*)strip + ((rb + 64 + g * 16) ^ sw));
        y[j] = __builtin_amdgcn_mfma_f32_16x16x32_bf16(vf0, sB0, y[j], 0, 0, 0);
        y[j] = __builtin_amdgcn_mfma_f32_16x16x32_bf16(vf1, sB1, y[j], 0, 0, 0);
    }

    float lsum = 0.f, lsq = 0.f;
    #pragma unroll
    for (int j = 0; j < 4; ++j)
        #pragma unroll
        for (int r = 0; r < 4; ++r) {
            float vy = y[j][r];
            lsum += vy; lsq += vy * vy;
        }
    #pragma unroll
    for (int m = 32; m; m >>= 1) {
        lsum += __shfl_xor(lsum, m, 64);
        lsq  += __shfl_xor(lsq,  m, 64);
    }
    if (l == 0) { red[w] = lsum; red[4 + w] = lsq; }

    #pragma unroll
    for (int j = 0; j < 4; ++j)
        #pragma unroll
        for (int r = 0; r < 4; ++r)
            tr[j * 16 + lr][16 * w + g * 4 + r] = y[j][r];
    __syncthreads();

    if (tid == 0) {
        float* ps = psums + ((size_t)bh * 32 + c) * 2;
        ps[0] = red[0] + red[1] + red[2] + red[3];
        ps[1] = red[4] + red[5] + red[6] + red[7];
    }

    #pragma unroll
    for (int u = 0; u < 4; ++u) {
        int row  = (tid >> 4) + u * 16;
        int col4 = (tid & 15) * 4;
        *(v4f*)&Y[(size_t)(b * TSEQ + 64 * c + row) * DM + h * 64 + col4] =
            *(const v4f*)&tr[row][col4];
    }
}

// ---------------------------------------------------------------------------
// GroupNorm finalize: per (b, channel) scale/shift from chunk partials
// ---------------------------------------------------------------------------
__global__ __launch_bounds__(256) void gn_finalize(
    const float* __restrict__ psums,
    const float* __restrict__ gnw, const float* __restrict__ gnb,
    float* __restrict__ scale, float* __restrict__ shift)
{
    int idx = blockIdx.x * 256 + threadIdx.x;
    if (idx >= NB * DM) return;
    int bb = idx >> 10;
    int ch = idx & (DM - 1);
    int hh = ch >> 6;
    int bh = bb * 16 + hh;

    float s = 0.f, q = 0.f;
    #pragma unroll
    for (int k = 0; k < 32; ++k) {
        s += psums[((size_t)bh * 32 + k) * 2];
        q += psums[((size_t)bh * 32 + k) * 2 + 1];
    }
    const float n = (float)(DH * TSEQ);
    float mean = s / n;
    float var  = q / n - mean * mean;
    float rstd = rsqrtf(var + GN_EPS);
    float sc = rstd * gnw[ch];
    scale[idx] = sc;
    shift[idx] = gnb[ch] - mean * sc;
}

// ---------------------------------------------------------------------------
// Apply GN -> bf16 (input to the output projection)
// ---------------------------------------------------------------------------
__global__ __launch_bounds__(256) void gn_apply(
    const float* __restrict__ Y, const float* __restrict__ scale,
    const float* __restrict__ shift, short* __restrict__ Ybf)
{
    const int total4 = (NB * TSEQ * DM) / 4;
    for (int i = blockIdx.x * 256 + threadIdx.x; i < total4;
         i += gridDim.x * 256) {
        int e = i * 4;
        int c = e & (DM - 1);
        int bb = e >> 21;
        v4f yv = *(const v4f*)(Y + e);
        v4f sc = *(const v4f*)(scale + bb * DM + c);
        v4f sh = *(const v4f*)(shift + bb * DM + c);
        v4s o;
        #pragma unroll
        for (int j = 0; j < 4; ++j) o[j] = f2bf(yv[j] * sc[j] + sh[j]);
        *(v4s*)(Ybf + e) = o;
    }
}

// ---------------------------------------------------------------------------
// Output projection: out = Ybf @ Wo^T, fp32 out.  m97-style main loop.
// ---------------------------------------------------------------------------
__global__ __launch_bounds__(256, 3) void gemm_out_mfma(
    const short* __restrict__ Ybf, const short* __restrict__ Wob,
    float* __restrict__ out)
{
    const int n0 = blockIdx.x * 128, m0 = blockIdx.y * 128;
    const int t = threadIdx.x, l = t & 63, w = t >> 6;
    const int wr = (w >> 1) * 64, wc = (w & 1) * 64;
    const int lr = l & 15, g = l >> 4;

    __shared__ short As[128 * 64];
    __shared__ short Bs[128 * 64];

    v4f acc[4][4];
    #pragma unroll
    for (int i = 0; i < 4; ++i)
        #pragma unroll
        for (int j = 0; j < 4; ++j) acc[i][j] = (v4f){0.f, 0.f, 0.f, 0.f};

    const char* Agp = (const char*)(Ybf + (size_t)m0 * DM);
    const char* Bgp = (const char*)(Wob + (size_t)n0 * DM);

    int soff[4], sdst[4];
    #pragma unroll
    for (int p = 0; p < 4; ++p) {
        int i = p * 256 + t;
        int row = i >> 3;
        int cp  = (i & 7) * 16;
        soff[p] = row * (DM * 2) + (cp ^ ((row & 7) << 4));
        sdst[p] = (p * 256 + (t & 192)) * 16;
    }
    const int swz = (lr & 7) << 4;

    for (int kt = 0; kt < DM / 64; ++kt) {
        const int kb = kt * 128;
        #pragma unroll
        for (int p = 0; p < 4; ++p) {
            gl_lds16(Agp + (size_t)soff[p] + kb, (char*)As + sdst[p]);
            gl_lds16(Bgp + (size_t)soff[p] + kb, (char*)Bs + sdst[p]);
        }
        asm volatile("s_waitcnt vmcnt(0)" ::: "memory");
        __syncthreads();

        v8s bfr[4][2];
        #pragma unroll
        for (int j = 0; j < 4; ++j) {
            int rowb = wc + j * 16 + lr;
            #pragma unroll
            for (int ks = 0; ks < 2; ++ks)
                bfr[j][ks] = *(const v8s*)((const char*)Bs + rowb * 128
                               + ((ks * 64 + g * 16) ^ swz));
        }
        #pragma unroll
        for (int i = 0; i < 4; ++i) {
            int rowa = wr + i * 16 + lr;
            v8s a0 = *(const v8s*)((const char*)As + rowa * 128 + ((g * 16) ^ swz));
            v8s a1 = *(const v8s*)((const char*)As + rowa * 128 + ((64 + g * 16) ^ swz));
            #pragma unroll
            for (int j = 0; j < 4; ++j) {
                acc[i][j] = __builtin_amdgcn_mfma_f32_16x16x32_bf16(
                    a0, bfr[j][0], acc[i][j], 0, 0, 0);
                acc[i][j] = __builtin_amdgcn_mfma_f32_16x16x32_bf16(
                    a1, bfr[j][1], acc[i][j], 0, 0, 0);
            }
        }
        __syncthreads();
    }

    #pragma unroll
    for (int i = 0; i < 4; ++i) {
        int row = m0 + wr + i * 16 + g * 4;
        #pragma unroll
        for (int j = 0; j < 4; ++j) {
            int col = n0 + wc + j * 16 + lr;
            #pragma unroll
            for (int r = 0; r < 4; ++r)
                out[(size_t)(row + r) * DM + col] = acc[i][j][r];
        }
    }
}

// ---------------------------------------------------------------------------
extern "C" void kernel_launch(void* const* d_in, const int* in_sizes, int n_in,
                              void* d_out, int out_size, void* d_ws, size_t ws_size,
                              hipStream_t stream)
{
    const float* x   = (const float*)d_in[0];
    const float* Wq  = (const float*)d_in[1];
    const float* Wk  = (const float*)d_in[2];
    const float* Wv  = (const float*)d_in[3];
    const float* Wo  = (const float*)d_in[4];
    const float* gnw = (const float*)d_in[5];
    const float* gnb = (const float*)d_in[6];
    float* out = (float*)d_out;

    char* wsb = (char*)d_ws;
    size_t o = 0;
    float* Y    = (float*)(wsb + o); o += (size_t)NB * TSEQ * DM * 4;
    short* Qb   = (short*)(wsb + o); o += (size_t)NB * TSEQ * DM * 2;
    short* Kb   = (short*)(wsb + o); o += (size_t)NB * TSEQ * DM * 2;
    short* Kt   = (short*)(wsb + o); o += (size_t)NB * TSEQ * DM * 2;
    short* Vt   = (short*)(wsb + o); o += (size_t)NB * TSEQ * DM * 2;
    short* xbf  = (short*)(wsb + o); o += (size_t)NB * TSEQ * DM * 2;
    short* wbf  = (short*)(wsb + o); o += (size_t)4 * DM * DM * 2;
    short* Ybf  = (short*)(wsb + o); o += (size_t)NB * TSEQ * DM * 2;
    float* psums = (float*)(wsb + o); o += (size_t)32 * 32 * 2 * 4;
    float* scale = (float*)(wsb + o); o += (size_t)NB * DM * 4;
    float* shift = (float*)(wsb + o); o += (size_t)NB * DM * 4;
    if (ws_size < o) return;

    short* At = xbf;   // aliases (stream-ordered): xbf dead after gemm_qkv
    short* St = Ybf;   // St consumed by chunk_out before gn_apply writes Ybf

    cast_kernel<<<2048, 256, 0, stream>>>(x, Wq, Wk, Wv, Wo, xbf, wbf);
    gemm_qkv_8ph<<<dim3(192), 512, 0, stream>>>(xbf, wbf, Qb, Kb, Kt, Vt);
    chunk_kv<<<dim3(1024), 256, 0, stream>>>(Kt, Vt, At);
    chunk_scan<<<dim3(512), 256, 0, stream>>>(At, St);
    chunk_out<<<dim3(1024), 256, 0, stream>>>(Qb, Kb, Vt, St, Y, psums);
    gn_finalize<<<dim3((NB * DM + 255) / 256), 256, 0, stream>>>(
        psums, gnw, gnb, scale, shift);
    gn_apply<<<2048, 256, 0, stream>>>(Y, scale, shift, Ybf);
    gemm_out_mfma<<<dim3(DM / 128, (NB * TSEQ) / 128), 256, 0, stream>>>(
        Ybf, wbf + 3 * (size_t)DM * DM, out);
}

// Round 13
// 95.690 us; speedup vs baseline: 1.0904x; 1.0904x over previous
//
#include <hip/hip_runtime.h>
#include <math.h>

#define TSEQ 2048
#define NB   2
#define DM   1024
#define NH   16
#define DH   64
#define GN_EPS 1e-5f

typedef short v8s __attribute__((ext_vector_type(8)));
typedef short v4s __attribute__((ext_vector_type(4)));
typedef float v4f __attribute__((ext_vector_type(4)));

__device__ __forceinline__ short f2bf(float f) {
    union { float f; unsigned u; } c; c.f = f;
    unsigned u = c.u;
    unsigned r = (u + 0x7fffu + ((u >> 16) & 1u)) >> 16;   // RNE
    return (short)r;
}
__device__ __forceinline__ float bf2f(short s) {
    union { unsigned u; float f; } c; c.u = ((unsigned)(unsigned short)s) << 16;
    return c.f;
}

// pack two f32 -> two bf16 in one instruction (no builtin on gfx950)
__device__ __forceinline__ unsigned cvtpk_bf16(float lo, float hi) {
    unsigned r;
    asm("v_cvt_pk_bf16_f32 %0, %1, %2" : "=v"(r) : "v"(lo), "v"(hi));
    return r;
}

// async global->LDS, 16B per lane.  LDS dest = wave-uniform base + lane*16.
__device__ __forceinline__ void gl_lds16(const void* g, void* l) {
    __builtin_amdgcn_global_load_lds(
        (const __attribute__((address_space(1))) void*)g,
        (__attribute__((address_space(3))) void*)l, 16, 0, 0);
}

// ---------------------------------------------------------------------------
// cast x and the 4 weight matrices to bf16
// ---------------------------------------------------------------------------
__global__ __launch_bounds__(256) void cast_kernel(
    const float* __restrict__ x,
    const float* __restrict__ Wq, const float* __restrict__ Wk,
    const float* __restrict__ Wv, const float* __restrict__ Wo,
    short* __restrict__ xbf, short* __restrict__ wbf)
{
    const int NX = NB * TSEQ * DM;            // 4,194,304
    const int NW = DM * DM;                   // 1,048,576
    const int total4 = (NX + 4 * NW) / 4;     // 2,097,152
    for (int i = blockIdx.x * 256 + threadIdx.x; i < total4;
         i += gridDim.x * 256) {
        int e = i * 4;
        const float* src; short* dst;
        if (e < NX) { src = x + e; dst = xbf + e; }
        else {
            int o = e - NX;
            int w = o >> 20;
            int r = o & (NW - 1);
            src = (w == 0 ? Wq : w == 1 ? Wk : w == 2 ? Wv : Wo) + r;
            dst = wbf + o;
        }
        v4f v = *(const v4f*)src;
        v4s s;
        #pragma unroll
        for (int j = 0; j < 4; ++j) s[j] = f2bf(v[j]);
        *(v4s*)dst = s;
    }
}

// ---------------------------------------------------------------------------
// QKV projection, bf16 MFMA, m97-style staged main loop (proven 622 TF here;
// the 8-phase port regressed at this shape -- reverted).
// z=0: Q' = Q * gamma_h^(t&63) / 8          (row-major Qb)
// z=1: K' = K * gamma_h^-(t&63)             (row-major Kb AND transposed Kt)
// z=2: V  -> transposed Vt[b][h*64+d][t]
// ---------------------------------------------------------------------------
__global__ __launch_bounds__(256, 3) void gemm_qkv_mfma(
    const short* __restrict__ xbf, const short* __restrict__ wbf,
    short* __restrict__ Qb, short* __restrict__ Kb,
    short* __restrict__ Kt, short* __restrict__ Vt)
{
    const int z = blockIdx.z;
    const short* __restrict__ Bmat = wbf + (size_t)z * (DM * DM);
    const int n0 = blockIdx.x * 128, m0 = blockIdx.y * 128;
    const int t = threadIdx.x, l = t & 63, w = t >> 6;
    const int wr = (w >> 1) * 64, wc = (w & 1) * 64;
    const int lr = l & 15, g = l >> 4, lg4 = g * 4;

    __shared__ short As[128 * 64];
    __shared__ short Bs[128 * 64];

    v4f acc[4][4];
    #pragma unroll
    for (int i = 0; i < 4; ++i)
        #pragma unroll
        for (int j = 0; j < 4; ++j) acc[i][j] = (v4f){0.f, 0.f, 0.f, 0.f};

    const char* Agp = (const char*)(xbf  + (size_t)m0 * DM);
    const char* Bgp = (const char*)(Bmat + (size_t)n0 * DM);

    int soff[4], sdst[4];
    #pragma unroll
    for (int p = 0; p < 4; ++p) {
        int i = p * 256 + t;
        int row = i >> 3;
        int cp  = (i & 7) * 16;
        soff[p] = row * (DM * 2) + (cp ^ ((row & 7) << 4));
        sdst[p] = (p * 256 + (t & 192)) * 16;      // wave-uniform base
    }
    const int swz = (lr & 7) << 4;

    for (int kt = 0; kt < DM / 64; ++kt) {
        const int kb = kt * 128;
        #pragma unroll
        for (int p = 0; p < 4; ++p) {
            gl_lds16(Agp + (size_t)soff[p] + kb, (char*)As + sdst[p]);
            gl_lds16(Bgp + (size_t)soff[p] + kb, (char*)Bs + sdst[p]);
        }
        asm volatile("s_waitcnt vmcnt(0)" ::: "memory");
        __syncthreads();

        v8s bfr[4][2];
        #pragma unroll
        for (int j = 0; j < 4; ++j) {
            int rowb = wc + j * 16 + lr;
            #pragma unroll
            for (int ks = 0; ks < 2; ++ks)
                bfr[j][ks] = *(const v8s*)((const char*)Bs + rowb * 128
                               + ((ks * 64 + g * 16) ^ swz));
        }
        #pragma unroll
        for (int i = 0; i < 4; ++i) {
            int rowa = wr + i * 16 + lr;
            v8s a0 = *(const v8s*)((const char*)As + rowa * 128 + ((g * 16) ^ swz));
            v8s a1 = *(const v8s*)((const char*)As + rowa * 128 + ((64 + g * 16) ^ swz));
            #pragma unroll
            for (int j = 0; j < 4; ++j) {
                acc[i][j] = __builtin_amdgcn_mfma_f32_16x16x32_bf16(
                    a0, bfr[j][0], acc[i][j], 0, 0, 0);
                acc[i][j] = __builtin_amdgcn_mfma_f32_16x16x32_bf16(
                    a1, bfr[j][1], acc[i][j], 0, 0, 0);
            }
        }
        __syncthreads();
    }

    if (z == 0) {
        float l2gj[4];
        #pragma unroll
        for (int j = 0; j < 4; ++j) {
            int hh = (n0 + wc + j * 16 + lr) >> 6;
            l2gj[j] = log2f(1.0f - exp2f(-5.0f - (float)hh));
        }
        #pragma unroll
        for (int i = 0; i < 4; ++i) {
            int row = m0 + wr + i * 16 + lg4;
            #pragma unroll
            for (int j = 0; j < 4; ++j) {
                int col = n0 + wc + j * 16 + lr;
                #pragma unroll
                for (int r = 0; r < 4; ++r) {
                    int tl = (row + r) & 63;
                    float fac = exp2f(fmaf(l2gj[j], (float)tl, -3.0f));
                    Qb[(size_t)(row + r) * DM + col] = f2bf(acc[i][j][r] * fac);
                }
            }
        }
    } else if (z == 1) {
        float l2gj[4];
        #pragma unroll
        for (int j = 0; j < 4; ++j) {
            int hh = (n0 + wc + j * 16 + lr) >> 6;
            l2gj[j] = -log2f(1.0f - exp2f(-5.0f - (float)hh));
        }
        #pragma unroll
        for (int i = 0; i < 4; ++i) {
            int row  = m0 + wr + i * 16 + lg4;
            int bidx = row >> 11, tb = row & (TSEQ - 1);
            #pragma unroll
            for (int j = 0; j < 4; ++j) {
                int col = n0 + wc + j * 16 + lr;
                v4s pk;
                #pragma unroll
                for (int r = 0; r < 4; ++r) {
                    int tl = (row + r) & 63;
                    float fac = exp2f(l2gj[j] * (float)tl);
                    short bv = f2bf(acc[i][j][r] * fac);
                    Kb[(size_t)(row + r) * DM + col] = bv;
                    pk[r] = bv;
                }
                *(v4s*)(Kt + ((size_t)bidx << 21) + ((size_t)col << 11) + tb) = pk;
            }
        }
    } else {
        #pragma unroll
        for (int i = 0; i < 4; ++i) {
            int row  = m0 + wr + i * 16 + lg4;
            int bidx = row >> 11, tb = row & (TSEQ - 1);
            #pragma unroll
            for (int j = 0; j < 4; ++j) {
                int col = n0 + wc + j * 16 + lr;
                v4s pk;
                #pragma unroll
                for (int r = 0; r < 4; ++r) pk[r] = f2bf(acc[i][j][r]);
                *(v4s*)(Vt + ((size_t)bidx << 21) + ((size_t)col << 11) + tb) = pk;
            }
        }
    }
}

// ---------------------------------------------------------------------------
// chunk_kv: per (b,h,chunk) compute A_c^T[dv][dk] = sum_jl V[jl][dv]*K'[jl][dk]
// ---------------------------------------------------------------------------
__global__ __launch_bounds__(256, 2) void chunk_kv(
    const short* __restrict__ Kt, const short* __restrict__ Vt,
    short* __restrict__ At)
{
    const int bid = blockIdx.x;                // 1024
    const int c = bid & 31, bh = bid >> 5;
    const int b = bh >> 4, h = bh & 15;
    const int tid = threadIdx.x, l = tid & 63, w = tid >> 6;
    const int lr = l & 15, g = l >> 4;

    const size_t rowbase = ((size_t)b * DM + h * 64);

    v8s kf[2], vf[4][2];
    {
        const short* kp = Kt + (rowbase + 16 * w + lr) * TSEQ + 64 * c;
        kf[0] = *(const v8s*)(kp + g * 8);
        kf[1] = *(const v8s*)(kp + 32 + g * 8);
    }
    #pragma unroll
    for (int j = 0; j < 4; ++j) {
        const short* vp = Vt + (rowbase + j * 16 + lr) * TSEQ + 64 * c;
        vf[j][0] = *(const v8s*)(vp + g * 8);
        vf[j][1] = *(const v8s*)(vp + 32 + g * 8);
    }

    v4f acc[4];
    #pragma unroll
    for (int j = 0; j < 4; ++j) acc[j] = (v4f){0.f, 0.f, 0.f, 0.f};

    #pragma unroll
    for (int j = 0; j < 4; ++j) {
        acc[j] = __builtin_amdgcn_mfma_f32_16x16x32_bf16(kf[0], vf[j][0], acc[j], 0, 0, 0);
        acc[j] = __builtin_amdgcn_mfma_f32_16x16x32_bf16(kf[1], vf[j][1], acc[j], 0, 0, 0);
    }

    short* Ab = At + (((size_t)bh * 32 + c) << 12);
    #pragma unroll
    for (int j = 0; j < 4; ++j) {
        v4s pk;
        #pragma unroll
        for (int r = 0; r < 4; ++r) pk[r] = f2bf(acc[j][r]);
        *(v4s*)(Ab + (j * 16 + lr) * 64 + 16 * w + g * 4) = pk;
    }
}

// ---------------------------------------------------------------------------
// chunk_scan: State_c = gamma^64 * (State_{c-1} + A_{c-1})
// ---------------------------------------------------------------------------
__global__ __launch_bounds__(256) void chunk_scan(
    const short* __restrict__ At, short* __restrict__ St)
{
    const int idx = blockIdx.x * 256 + threadIdx.x;   // 131072
    const int bh = idx >> 12;
    const int h  = bh & 15;
    const float l2g = log2f(1.0f - exp2f(-5.0f - (float)h));
    const float g64 = exp2f(l2g * 64.0f);

    const size_t base = ((size_t)bh << 17) + (idx & 4095);
    float state = 0.0f;
    #pragma unroll
    for (int c = 1; c < 32; ++c) {
        float a = bf2f(At[base + ((size_t)(c - 1) << 12)]);
        state = g64 * (state + a);
        St[base + ((size_t)c << 12)] = f2bf(state);
    }
}

// ---------------------------------------------------------------------------
// chunk_out: Y_c^T = StateT_c.Q'^T + V^T.(mask(Q'K'^T)); writes UN-NORMALIZED
// Ybf (bf16) -- GN is folded into Wo2/bias downstream.  GN partials -> plain
// stores to psums (no atomics).
// ---------------------------------------------------------------------------
__global__ __launch_bounds__(256, 2) void chunk_out(
    const short* __restrict__ Qb, const short* __restrict__ Kb,
    const short* __restrict__ Vt, const short* __restrict__ St,
    short* __restrict__ Ybf, float* __restrict__ psums)
{
    const int bid = blockIdx.x;                 // 1024
    const int xcd = bid & 7, r8 = bid >> 3;
    const int bh  = xcd * 4 + (r8 >> 5);
    const int c   = r8 & 31;
    const int b = bh >> 4, h = bh & 15;
    const int tid = threadIdx.x, l = tid & 63, w = tid >> 6;
    const int lr = l & 15, g = l >> 4;

    __shared__ short strip[64 * 64];
    __shared__ float tr[64][68];
    __shared__ float red[8];

    const size_t rowQK = ((size_t)(b * TSEQ + 64 * c)) * DM + h * 64;

    v8s qf[4][2];
    #pragma unroll
    for (int j = 0; j < 4; ++j) {
        const short* qp = Qb + rowQK + (size_t)(j * 16 + lr) * DM;
        qf[j][0] = *(const v8s*)(qp + g * 8);
        qf[j][1] = *(const v8s*)(qp + 32 + g * 8);
    }
    v8s kf0, kf1;
    {
        const short* kp = Kb + rowQK + (size_t)(16 * w + lr) * DM;
        kf0 = *(const v8s*)(kp + g * 8);
        kf1 = *(const v8s*)(kp + 32 + g * 8);
    }
    v8s sf0 = {}, sf1 = {};
    if (c > 0) {
        const short* sp = St + (((size_t)bh * 32 + c) << 12) + (16 * w + lr) * 64;
        sf0 = *(const v8s*)(sp + g * 8);
        sf1 = *(const v8s*)(sp + 32 + g * 8);
    }
    v8s vf0, vf1;
    {
        const short* vp = Vt + ((size_t)(b * DM + h * 64) + 16 * w + lr) * TSEQ
                          + 64 * c;
        vf0 = *(const v8s*)(vp + g * 8);
        vf1 = *(const v8s*)(vp + 32 + g * 8);
    }

    v4f s[4];
    #pragma unroll
    for (int j = 0; j < 4; ++j) {
        v4f a = (v4f){0.f, 0.f, 0.f, 0.f};
        a = __builtin_amdgcn_mfma_f32_16x16x32_bf16(kf0, qf[j][0], a, 0, 0, 0);
        a = __builtin_amdgcn_mfma_f32_16x16x32_bf16(kf1, qf[j][1], a, 0, 0, 0);
        s[j] = a;
    }

    v4f y[4];
    #pragma unroll
    for (int j = 0; j < 4; ++j) y[j] = (v4f){0.f, 0.f, 0.f, 0.f};
    if (c > 0) {
        #pragma unroll
        for (int j = 0; j < 4; ++j) {
            y[j] = __builtin_amdgcn_mfma_f32_16x16x32_bf16(sf0, qf[j][0], y[j], 0, 0, 0);
            y[j] = __builtin_amdgcn_mfma_f32_16x16x32_bf16(sf1, qf[j][1], y[j], 0, 0, 0);
        }
    }

    #pragma unroll
    for (int j = 0; j < 4; ++j) {
        v4f vv = s[j];
        #pragma unroll
        for (int r = 0; r < 4; ++r)
            if ((j * 16 + lr) - (16 * w + g * 4 + r) < 0) vv[r] = 0.0f;
        unsigned u0 = cvtpk_bf16(vv[0], vv[1]);
        unsigned u1 = cvtpk_bf16(vv[2], vv[3]);
        int byte = ((j * 16 + lr) * 128 + 32 * w + g * 8) ^ ((lr & 7) << 4);
        *(unsigned long long*)((char*)strip + byte) =
            (unsigned long long)u0 | ((unsigned long long)u1 << 32);
    }
    __syncthreads();

    #pragma unroll
    for (int j = 0; j < 4; ++j) {
        int rb = (j * 16 + lr) * 128;
        int sw = (lr & 7) << 4;
        v8s sB0 = *(const v8s*)((char*)strip + ((rb + g * 16) ^ sw));
        v8s sB1 = *(const v8s*)((char*)strip + ((rb + 64 + g * 16) ^ sw));
        y[j] = __builtin_amdgcn_mfma_f32_16x16x32_bf16(vf0, sB0, y[j], 0, 0, 0);
        y[j] = __builtin_amdgcn_mfma_f32_16x16x32_bf16(vf1, sB1, y[j], 0, 0, 0);
    }

    float lsum = 0.f, lsq = 0.f;
    #pragma unroll
    for (int j = 0; j < 4; ++j)
        #pragma unroll
        for (int r = 0; r < 4; ++r) {
            float vy = y[j][r];
            lsum += vy; lsq += vy * vy;
        }
    #pragma unroll
    for (int m = 32; m; m >>= 1) {
        lsum += __shfl_xor(lsum, m, 64);
        lsq  += __shfl_xor(lsq,  m, 64);
    }
    if (l == 0) { red[w] = lsum; red[4 + w] = lsq; }

    #pragma unroll
    for (int j = 0; j < 4; ++j)
        #pragma unroll
        for (int r = 0; r < 4; ++r)
            tr[j * 16 + lr][16 * w + g * 4 + r] = y[j][r];
    __syncthreads();

    if (tid == 0) {
        float* ps = psums + ((size_t)bh * 32 + c) * 2;
        ps[0] = red[0] + red[1] + red[2] + red[3];
        ps[1] = red[4] + red[5] + red[6] + red[7];
    }

    #pragma unroll
    for (int u = 0; u < 4; ++u) {
        int row  = (tid >> 4) + u * 16;
        int col4 = (tid & 15) * 4;
        v4f val = *(const v4f*)&tr[row][col4];
        v4s pk;
        #pragma unroll
        for (int r = 0; r < 4; ++r) pk[r] = f2bf(val[r]);
        *(v4s*)&Ybf[(size_t)(b * TSEQ + 64 * c + row) * DM + h * 64 + col4] = pk;
    }
}

// ---------------------------------------------------------------------------
// GroupNorm finalize: per (b, channel) scale/shift from chunk partials
// ---------------------------------------------------------------------------
__global__ __launch_bounds__(256) void gn_finalize(
    const float* __restrict__ psums,
    const float* __restrict__ gnw, const float* __restrict__ gnb,
    float* __restrict__ scale, float* __restrict__ shift)
{
    int idx = blockIdx.x * 256 + threadIdx.x;
    if (idx >= NB * DM) return;
    int bb = idx >> 10;
    int ch = idx & (DM - 1);
    int hh = ch >> 6;
    int bh = bb * 16 + hh;

    float s = 0.f, q = 0.f;
    #pragma unroll
    for (int k = 0; k < 32; ++k) {
        s += psums[((size_t)bh * 32 + k) * 2];
        q += psums[((size_t)bh * 32 + k) * 2 + 1];
    }
    const float n = (float)(DH * TSEQ);
    float mean = s / n;
    float var  = q / n - mean * mean;
    float rstd = rsqrtf(var + GN_EPS);
    float sc = rstd * gnw[ch];
    scale[idx] = sc;
    shift[idx] = gnb[ch] - mean * sc;
}

// ---------------------------------------------------------------------------
// wo_prep: Wo2[b][n][k] = bf16(Wo[n][k] * scale[b][k]);
//          bias[b][n]   = sum_k shift[b][k] * Wo[n][k].
// One wave per (b,n): lane l handles k = l*16..l*16+15.  grid 512 x 256thr.
// ---------------------------------------------------------------------------
__global__ __launch_bounds__(256) void wo_prep(
    const short* __restrict__ Wob, const float* __restrict__ scale,
    const float* __restrict__ shift,
    short* __restrict__ Wo2, float* __restrict__ bias)
{
    const int tid = threadIdx.x, l = tid & 63, w = tid >> 6;
    const int bn = blockIdx.x * 4 + w;        // 0..2047
    const int b = bn >> 10, n = bn & 1023;
    const int k0 = l * 16;

    const short* wp = Wob + (size_t)n * DM + k0;
    v8s w0 = *(const v8s*)wp;
    v8s w1 = *(const v8s*)(wp + 8);
    const float* sc = scale + b * DM + k0;
    const float* sh = shift + b * DM + k0;

    v8s o0, o1;
    float bsum = 0.f;
    #pragma unroll
    for (int j = 0; j < 8; ++j) {
        float wf = bf2f(w0[j]);
        o0[j] = f2bf(wf * sc[j]);
        bsum = fmaf(sh[j], wf, bsum);
    }
    #pragma unroll
    for (int j = 0; j < 8; ++j) {
        float wf = bf2f(w1[j]);
        o1[j] = f2bf(wf * sc[8 + j]);
        bsum = fmaf(sh[8 + j], wf, bsum);
    }
    short* op = Wo2 + ((size_t)b * DM + n) * DM + k0;
    *(v8s*)op = o0;
    *(v8s*)(op + 8) = o1;

    #pragma unroll
    for (int m = 32; m; m >>= 1) bsum += __shfl_xor(bsum, m, 64);
    if (l == 0) bias[bn] = bsum;
}

// ---------------------------------------------------------------------------
// Output projection: out = Ybf @ Wo2[b]^T + bias[b], fp32 out.  m97 loop.
// b = m0 >> 11 is block-uniform (m-tile never crosses the batch boundary).
// ---------------------------------------------------------------------------
__global__ __launch_bounds__(256, 3) void gemm_out_mfma(
    const short* __restrict__ Ybf, const short* __restrict__ Wo2,
    const float* __restrict__ bias, float* __restrict__ out)
{
    const int n0 = blockIdx.x * 128, m0 = blockIdx.y * 128;
    const int b = m0 >> 11;
    const int t = threadIdx.x, l = t & 63, w = t >> 6;
    const int wr = (w >> 1) * 64, wc = (w & 1) * 64;
    const int lr = l & 15, g = l >> 4;

    __shared__ short As[128 * 64];
    __shared__ short Bs[128 * 64];

    v4f acc[4][4];
    #pragma unroll
    for (int i = 0; i < 4; ++i)
        #pragma unroll
        for (int j = 0; j < 4; ++j) acc[i][j] = (v4f){0.f, 0.f, 0.f, 0.f};

    const char* Agp = (const char*)(Ybf + (size_t)m0 * DM);
    const char* Bgp = (const char*)(Wo2 + (size_t)b * DM * DM + (size_t)n0 * DM);

    int soff[4], sdst[4];
    #pragma unroll
    for (int p = 0; p < 4; ++p) {
        int i = p * 256 + t;
        int row = i >> 3;
        int cp  = (i & 7) * 16;
        soff[p] = row * (DM * 2) + (cp ^ ((row & 7) << 4));
        sdst[p] = (p * 256 + (t & 192)) * 16;
    }
    const int swz = (lr & 7) << 4;

    for (int kt = 0; kt < DM / 64; ++kt) {
        const int kb = kt * 128;
        #pragma unroll
        for (int p = 0; p < 4; ++p) {
            gl_lds16(Agp + (size_t)soff[p] + kb, (char*)As + sdst[p]);
            gl_lds16(Bgp + (size_t)soff[p] + kb, (char*)Bs + sdst[p]);
        }
        asm volatile("s_waitcnt vmcnt(0)" ::: "memory");
        __syncthreads();

        v8s bfr[4][2];
        #pragma unroll
        for (int j = 0; j < 4; ++j) {
            int rowb = wc + j * 16 + lr;
            #pragma unroll
            for (int ks = 0; ks < 2; ++ks)
                bfr[j][ks] = *(const v8s*)((const char*)Bs + rowb * 128
                               + ((ks * 64 + g * 16) ^ swz));
        }
        #pragma unroll
        for (int i = 0; i < 4; ++i) {
            int rowa = wr + i * 16 + lr;
            v8s a0 = *(const v8s*)((const char*)As + rowa * 128 + ((g * 16) ^ swz));
            v8s a1 = *(const v8s*)((const char*)As + rowa * 128 + ((64 + g * 16) ^ swz));
            #pragma unroll
            for (int j = 0; j < 4; ++j) {
                acc[i][j] = __builtin_amdgcn_mfma_f32_16x16x32_bf16(
                    a0, bfr[j][0], acc[i][j], 0, 0, 0);
                acc[i][j] = __builtin_amdgcn_mfma_f32_16x16x32_bf16(
                    a1, bfr[j][1], acc[i][j], 0, 0, 0);
            }
        }
        __syncthreads();
    }

    #pragma unroll
    for (int i = 0; i < 4; ++i) {
        int row = m0 + wr + i * 16 + g * 4;
        #pragma unroll
        for (int j = 0; j < 4; ++j) {
            int col = n0 + wc + j * 16 + lr;
            float bv = bias[b * DM + col];
            #pragma unroll
            for (int r = 0; r < 4; ++r)
                out[(size_t)(row + r) * DM + col] = acc[i][j][r] + bv;
        }
    }
}

// ---------------------------------------------------------------------------
extern "C" void kernel_launch(void* const* d_in, const int* in_sizes, int n_in,
                              void* d_out, int out_size, void* d_ws, size_t ws_size,
                              hipStream_t stream)
{
    const float* x   = (const float*)d_in[0];
    const float* Wq  = (const float*)d_in[1];
    const float* Wk  = (const float*)d_in[2];
    const float* Wv  = (const float*)d_in[3];
    const float* Wo  = (const float*)d_in[4];
    const float* gnw = (const float*)d_in[5];
    const float* gnb = (const float*)d_in[6];
    float* out = (float*)d_out;

    char* wsb = (char*)d_ws;
    size_t o = 0;
    short* Qb   = (short*)(wsb + o); o += (size_t)NB * TSEQ * DM * 2;   // 8 MiB
    short* Kb   = (short*)(wsb + o); o += (size_t)NB * TSEQ * DM * 2;
    short* Kt   = (short*)(wsb + o); o += (size_t)NB * TSEQ * DM * 2;
    short* Vt   = (short*)(wsb + o); o += (size_t)NB * TSEQ * DM * 2;
    short* xbf  = (short*)(wsb + o); o += (size_t)NB * TSEQ * DM * 2;
    short* wbf  = (short*)(wsb + o); o += (size_t)4 * DM * DM * 2;      // 8 MiB
    short* Ybf  = (short*)(wsb + o); o += (size_t)NB * TSEQ * DM * 2;
    short* St   = (short*)(wsb + o); o += (size_t)NB * TSEQ * DM * 2;   // 8 MiB
    short* Wo2  = (short*)(wsb + o); o += (size_t)NB * DM * DM * 2;     // 4 MiB
    float* psums = (float*)(wsb + o); o += (size_t)32 * 32 * 2 * 4;
    float* scale = (float*)(wsb + o); o += (size_t)NB * DM * 4;
    float* shift = (float*)(wsb + o); o += (size_t)NB * DM * 4;
    float* bias  = (float*)(wsb + o); o += (size_t)NB * DM * 4;
    if (ws_size < o) return;

    short* At = xbf;   // alias (stream-ordered): xbf dead after gemm_qkv

    cast_kernel<<<2048, 256, 0, stream>>>(x, Wq, Wk, Wv, Wo, xbf, wbf);
    gemm_qkv_mfma<<<dim3(DM / 128, (NB * TSEQ) / 128, 3), 256, 0, stream>>>(
        xbf, wbf, Qb, Kb, Kt, Vt);
    chunk_kv<<<dim3(1024), 256, 0, stream>>>(Kt, Vt, At);
    chunk_scan<<<dim3(512), 256, 0, stream>>>(At, St);
    chunk_out<<<dim3(1024), 256, 0, stream>>>(Qb, Kb, Vt, St, Ybf, psums);
    gn_finalize<<<dim3((NB * DM + 255) / 256), 256, 0, stream>>>(
        psums, gnw, gnb, scale, shift);
    wo_prep<<<dim3(512), 256, 0, stream>>>(
        wbf + 3 * (size_t)DM * DM, scale, shift, Wo2, bias);
    gemm_out_mfma<<<dim3(DM / 128, (NB * TSEQ) / 128), 256, 0, stream>>>(
        Ybf, Wo2, bias, out);
}